// Round 1
// baseline (70.063 us; speedup 1.0000x reference)
//
#include <hip/hip_runtime.h>
#include <hip/hip_bf16.h>
#include <math.h>

// QCONV2d 5x5: out[b,c,h,w] = prod_{p=1..24} cos(x_patch[p] + w[p])
// patch p = di*5+dj, value x[b,c,h+di-2,w+dj-2] (zero padded 'same').
// Identity: cos(x+w) = cos(x)*cos(w) - sin(x)*sin(w) -> sincos each pixel ONCE,
// inner loop is pure FMA. Zero-pad => (cos,sin)=(1,0) => term = cos(w_p). Exact.

#define TILE_ROWS 16
#define HALO 2
#define SM_ROWS (TILE_ROWS + 2 * HALO)  // 20
#define SM_COLS (64 + 2 * HALO)         // 68

__global__ __launch_bounds__(256, 4)
void qconv5x5_kernel(const float* __restrict__ x, const float* __restrict__ w,
                     float* __restrict__ out)
{
    // (cos, sin) interleaved so neighbor fetch is one ds_read_b64
    __shared__ float2 sm[SM_ROWS][SM_COLS];
    __shared__ float2 smw[25];

    const int tid   = threadIdx.x;
    const int bid   = blockIdx.x;
    const int plane = bid >> 2;               // b*16 + c, 512 planes
    const int r0    = (bid & 3) * TILE_ROWS;  // strip start row

    const float* xp = x + plane * 64 * 64;

    if (tid < 25) {
        float s, c;
        __sincosf(w[tid], &s, &c);
        smw[tid] = make_float2(c, s);
    }

    // Stage strip rows [r0-2, r0+17], cols [-2, 65]; OOB -> (1,0).
    for (int i = tid; i < SM_ROWS * SM_COLS; i += 256) {
        int rr = i / SM_COLS;
        int cc = i - rr * SM_COLS;
        int gr = r0 + rr - HALO;
        int gc = cc - HALO;
        float c = 1.0f, s = 0.0f;
        if ((unsigned)gr < 64u && (unsigned)gc < 64u) {
            __sincosf(xp[gr * 64 + gc], &s, &c);
        }
        sm[rr][cc] = make_float2(c, s);
    }
    __syncthreads();

    // w sincos into registers (50 VGPRs) — broadcast-read once
    float cw[25], sw[25];
#pragma unroll
    for (int p = 0; p < 25; ++p) { cw[p] = smw[p].x; sw[p] = smw[p].y; }

    const int tx = tid & 63;   // output column (lane == col: coalesced)
    const int q  = tid >> 6;   // wave id: handles local rows q*4 .. q*4+3

    float prod[4] = {1.f, 1.f, 1.f, 1.f};

    // Sliding window: 8 neighborhood rows feed 4 consecutive output rows.
    // Output local row rl = q*4+ro needs tile rows rl..rl+4 (tile row 0 = r0-2).
#pragma unroll
    for (int nr = 0; nr < 8; ++nr) {
        const int tr = q * 4 + nr;
        float2 v[5];
#pragma unroll
        for (int dj = 0; dj < 5; ++dj) v[dj] = sm[tr][tx + dj];
#pragma unroll
        for (int ro = 0; ro < 4; ++ro) {
            const int di = nr - ro;
            if (di < 0 || di > 4) continue;
#pragma unroll
            for (int dj = 0; dj < 5; ++dj) {
                const int p = di * 5 + dj;
                if (p == 0) continue;   // reference skips patch index 0
                prod[ro] *= fmaf(v[dj].x, cw[p], -(v[dj].y * sw[p]));
            }
        }
    }

    float* op = out + plane * 64 * 64 + (r0 + q * 4) * 64 + tx;
#pragma unroll
    for (int ro = 0; ro < 4; ++ro) op[ro * 64] = prod[ro];
}

extern "C" void kernel_launch(void* const* d_in, const int* in_sizes, int n_in,
                              void* d_out, int out_size, void* d_ws, size_t ws_size,
                              hipStream_t stream) {
    const float* x = (const float*)d_in[0];   // [32,16,64,64]
    const float* w = (const float*)d_in[1];   // [25]
    float* out = (float*)d_out;               // [32,16,64,64]
    (void)in_sizes; (void)n_in; (void)out_size; (void)d_ws; (void)ws_size;

    const int planes = 32 * 16;               // 512
    dim3 grid(planes * (64 / TILE_ROWS));     // 2048 blocks
    dim3 block(256);
    qconv5x5_kernel<<<grid, block, 0, stream>>>(x, w, out);
}

// Round 2
// 68.818 us; speedup vs baseline: 1.0181x; 1.0181x over previous
//
#include <hip/hip_runtime.h>
#include <hip/hip_bf16.h>
#include <math.h>

// QCONV2d 5x5: out[b,c,h,w] = prod_{p=1..24} cos(x_patch[p] + w[p])
// Identity: cos(x+w) = cos(x)cos(w) - sin(x)sin(w). sincos(pixel) computed ONCE
// (staged in LDS as interleaved float2), sincos(w) computed once per thread and
// pinned to SGPRs via readfirstlane (wave-uniform -> frees 50 VGPRs; each
// v_fma/v_mul reads exactly 1 SGPR, which is legal).
// Zero pad => (cos,sin)=(1,0) => term = cos(w_p): matches reference exactly.

#define TR   32                 // output rows per block strip
#define SMR  (TR + 4)           // 36 staged rows (2 halo each side)
#define SMC  (64 + 4)           // 68 staged cols

__device__ __forceinline__ float uni(float v) {
    return __uint_as_float(__builtin_amdgcn_readfirstlane(__float_as_uint(v)));
}

__global__ __launch_bounds__(256)
void qconv5x5_kernel(const float* __restrict__ x, const float* __restrict__ w,
                     float* __restrict__ out)
{
    __shared__ float2 sm[SMR][SMC];   // (cos, sin) per pixel, 19.6 KB

    const int tid   = threadIdx.x;
    const int bid   = blockIdx.x;
    const int plane = bid >> 1;              // b*16 + c  (512 planes)
    const int r0    = (bid & 1) * TR;        // strip start row: 0 or 32

    // --- wave-uniform w-trig into SGPRs (no LDS, no VGPR arrays) ---
    float cw[25], sw[25];
#pragma unroll
    for (int p = 0; p < 25; ++p) {
        float s, c;
        __sincosf(w[p], &s, &c);
        cw[p] = uni(c);
        sw[p] = uni(s);
    }

    // --- stage strip rows [r0-2, r0+33], cols [-2, 65]; OOB -> (1,0) ---
    const float* xp = x + plane * 64 * 64;
    for (int i = tid; i < SMR * SMC; i += 256) {
        const int rr = i / SMC;
        const int cc = i - rr * SMC;
        const int gr = r0 + rr - 2;
        const int gc = cc - 2;
        float c = 1.0f, s = 0.0f;
        if ((unsigned)gr < 64u && (unsigned)gc < 64u) {
            __sincosf(xp[gr * 64 + gc], &s, &c);
        }
        sm[rr][cc] = make_float2(c, s);
    }
    __syncthreads();

    // --- compute: each thread owns one column x 8 consecutive output rows ---
    const int tx = tid & 63;    // output column (lane == col: coalesced)
    const int q  = tid >> 6;    // wave id: local output rows q*8 .. q*8+7

    float prod[8];
#pragma unroll
    for (int ro = 0; ro < 8; ++ro) prod[ro] = 1.0f;

    // Sliding window: 12 neighborhood rows feed 8 output rows.
    // Output local row rl = q*8+ro uses tile rows rl..rl+4 (tile row 0 = r0-2).
#pragma unroll
    for (int nr = 0; nr < 12; ++nr) {
        const int tr = q * 8 + nr;
        float2 v[5];
#pragma unroll
        for (int dj = 0; dj < 5; ++dj) v[dj] = sm[tr][tx + dj];
#pragma unroll
        for (int ro = 0; ro < 8; ++ro) {
            const int di = nr - ro;
            if (di < 0 || di > 4) continue;
#pragma unroll
            for (int dj = 0; dj < 5; ++dj) {
                const int p = di * 5 + dj;
                if (p == 0) continue;     // reference skips patch index 0
                prod[ro] *= fmaf(v[dj].x, cw[p], -(v[dj].y * sw[p]));
            }
        }
    }

    float* op = out + plane * 64 * 64 + (r0 + q * 8) * 64 + tx;
#pragma unroll
    for (int ro = 0; ro < 8; ++ro) op[ro * 64] = prod[ro];
}

extern "C" void kernel_launch(void* const* d_in, const int* in_sizes, int n_in,
                              void* d_out, int out_size, void* d_ws, size_t ws_size,
                              hipStream_t stream) {
    const float* x = (const float*)d_in[0];   // [32,16,64,64] f32
    const float* w = (const float*)d_in[1];   // [25] f32
    float* out = (float*)d_out;               // [32,16,64,64] f32
    (void)in_sizes; (void)n_in; (void)out_size; (void)d_ws; (void)ws_size;

    const int planes = 32 * 16;               // 512
    dim3 grid(planes * (64 / TR));            // 1024 blocks
    dim3 block(256);
    qconv5x5_kernel<<<grid, block, 0, stream>>>(x, w, out);
}

// Round 3
// 65.693 us; speedup vs baseline: 1.0665x; 1.0476x over previous
//
#include <hip/hip_runtime.h>
#include <hip/hip_bf16.h>
#include <math.h>

// QCONV2d 5x5: out[b,c,h,w] = prod_{p=1..24} cos(x_patch[p] + w[p])
// cos(x+w) = cos(x)cos(w) - sin(x)sin(w): sincos(pixel) once -> LDS float2;
// sincos(w) once PER LANE then v_readlane -> 50 SGPRs (wave-uniform).
// Each thread: 2 adjacent output cols x 4 rows; 6-pixel col window = 3 aligned
// ds_read_b128 per neighborhood row (vs 10 ds_read_b64). Zero pad => (1,0).

#define TR   32                 // output rows per block strip
#define SMR  (TR + 4)           // 36 staged rows
#define SMC  (64 + 4)           // 68 staged cols (544 B/row, 16B-multiple)

__device__ __forceinline__ float rdlane(float v, int lane) {
    return __uint_as_float(__builtin_amdgcn_readlane(__float_as_uint(v), lane));
}

__global__ __launch_bounds__(256)
void qconv5x5_kernel(const float* __restrict__ x, const float* __restrict__ w,
                     float* __restrict__ out)
{
    __shared__ alignas(16) float2 sm[SMR][SMC];   // (cos,sin), 19.6 KB

    const int tid   = threadIdx.x;
    const int bid   = blockIdx.x;
    const int plane = bid >> 1;              // 512 planes
    const int r0    = (bid & 1) * TR;        // strip start row: 0 or 32

    // --- w-trig: one sincos per lane, broadcast via readlane -> SGPRs ---
    const int lane = tid & 63;
    float sv, cv;
    __sincosf(w[lane < 25 ? lane : 0], &sv, &cv);
    float cw[25], sw[25];
#pragma unroll
    for (int p = 0; p < 25; ++p) {
        cw[p] = rdlane(cv, p);
        sw[p] = rdlane(sv, p);
    }

    // --- stage rows [r0-2, r0+33], cols [-2,65]; OOB -> (1,0) ---
    const float* xp = x + plane * 64 * 64;
    for (int i = tid; i < SMR * SMC; i += 256) {
        const int rr = i / SMC;
        const int cc = i - rr * SMC;
        const int gr = r0 + rr - 2;
        const int gc = cc - 2;
        float c = 1.0f, s = 0.0f;
        if ((unsigned)gr < 64u && (unsigned)gc < 64u) {
            __sincosf(xp[gr * 64 + gc], &s, &c);
        }
        sm[rr][cc] = make_float2(c, s);
    }
    __syncthreads();

    // --- compute: thread -> col-pair cp (cols 2cp,2cp+1), row-group rq ---
    const int cp = tid & 31;         // 0..31
    const int rq = tid >> 5;         // 0..7, output local rows rq*4..rq*4+3

    float prod[4][2];
#pragma unroll
    for (int ro = 0; ro < 4; ++ro) { prod[ro][0] = 1.f; prod[ro][1] = 1.f; }

    // 8 neighborhood rows feed 4 output rows. Output col e=2cp needs staged
    // cols e..e+4; odd col e+1 needs e+1..e+5 -> staged float4 idx cp,cp+1,cp+2.
#pragma unroll
    for (int nr = 0; nr < 8; ++nr) {
        const int tr = rq * 4 + nr;
        const float4* rowp = reinterpret_cast<const float4*>(&sm[tr][0]);
        float4 f0 = rowp[cp], f1 = rowp[cp + 1], f2 = rowp[cp + 2];
        float2 arr6[6] = { make_float2(f0.x, f0.y), make_float2(f0.z, f0.w),
                           make_float2(f1.x, f1.y), make_float2(f1.z, f1.w),
                           make_float2(f2.x, f2.y), make_float2(f2.z, f2.w) };
#pragma unroll
        for (int ro = 0; ro < 4; ++ro) {
            const int di = nr - ro;
            if (di < 0 || di > 4) continue;
#pragma unroll
            for (int dj = 0; dj < 5; ++dj) {
                const int p = di * 5 + dj;
#pragma unroll
                for (int pa = 0; pa < 2; ++pa) {
                    if (p == 0) continue;          // reference skips patch 0
                    const float2 v = arr6[dj + pa];
                    prod[ro][pa] *= fmaf(v.x, cw[p], -(v.y * sw[p]));
                }
            }
        }
    }

    float2* op = reinterpret_cast<float2*>(
        out + plane * 64 * 64 + (r0 + rq * 4) * 64 + 2 * cp);
#pragma unroll
    for (int ro = 0; ro < 4; ++ro)
        op[ro * 32] = make_float2(prod[ro][0], prod[ro][1]);
}

extern "C" void kernel_launch(void* const* d_in, const int* in_sizes, int n_in,
                              void* d_out, int out_size, void* d_ws, size_t ws_size,
                              hipStream_t stream) {
    const float* x = (const float*)d_in[0];   // [32,16,64,64] f32
    const float* w = (const float*)d_in[1];   // [25] f32
    float* out = (float*)d_out;               // [32,16,64,64] f32
    (void)in_sizes; (void)n_in; (void)out_size; (void)d_ws; (void)ws_size;

    dim3 grid(512 * (64 / TR));               // 1024 blocks
    dim3 block(256);
    qconv5x5_kernel<<<grid, block, 0, stream>>>(x, w, out);
}